// Round 6
// baseline (481.667 us; speedup 1.0000x reference)
//
#include <hip/hip_runtime.h>

#define NQ 4
#define DIM 16
#define E 2   // batch elements per thread (small -> low VGPR, high occupancy)

// o_q(b) = sum_{a<=c} hh_a hh_c * sum_{b<=d} ll_b ll_d * G_q[(a,c)][(b,d)]
// G: 10x10 float4 (1.6 KB LDS), built per-block from the weight unitary.
// Round-6: native __sinf/__cosf (ocml __sincosf was the hidden VALU+VGPR
// cost), E=2 + launch_bounds(256,4) for 4 waves/SIMD.

__global__ void __launch_bounds__(256, 4)
qlayer_kernel(const float4* __restrict__ x,
              const float* __restrict__ weights,
              float4* __restrict__ out, int B)
{
    __shared__ __align__(16) float2 WT[DIM][DIM];       // WT[j][i] = W[i][j]
    __shared__ __align__(16) float4 G4[100];            // G[(ac)*10+(bd)]

    constexpr int PA[10] = {0,0,0,0,1,1,1,2,2,3};
    constexpr int PC[10] = {0,1,2,3,1,2,3,2,3,3};

    // ---- phase 1: threads 0..15 build W columns (verified) ----
    if (threadIdx.x < DIM) {
        const int k = threadIdx.x;
        float sre[DIM], sim[DIM];
#pragma unroll
        for (int i = 0; i < DIM; ++i) { sre[i] = (i == k) ? 1.f : 0.f; sim[i] = 0.f; }
#pragma unroll
        for (int l = 0; l < 3; ++l) {
#pragma unroll
            for (int p = 0; p < NQ; ++p) {
                const float h = 0.5f * weights[l * NQ + p];
                const float s = __sinf(h), c = __cosf(h);
                const int mask = 1 << (NQ - 1 - p);
#pragma unroll
                for (int i = 0; i < DIM; ++i) {
                    if (i & mask) continue;
                    const int jj = i | mask;
                    const float ar = sre[i], ai = sim[i];
                    const float br = sre[jj], bi = sim[jj];
                    sre[i]  = c * ar + s * bi;
                    sim[i]  = c * ai - s * br;
                    sre[jj] = c * br + s * ai;
                    sim[jj] = c * bi - s * ar;
                }
            }
#pragma unroll
            for (int p = 0; p < NQ; ++p) {
                const int t = (p + 1) % NQ;
                float tr[DIM], ti[DIM];
#pragma unroll
                for (int i = 0; i < DIM; ++i) {
                    const int src = i ^ ((((i >> (NQ - 1 - p)) & 1)) << (NQ - 1 - t));
                    tr[i] = sre[src]; ti[i] = sim[src];
                }
#pragma unroll
                for (int i = 0; i < DIM; ++i) { sre[i] = tr[i]; sim[i] = ti[i]; }
            }
        }
#pragma unroll
        for (int i = 0; i < DIM; ++i) WT[k][i] = make_float2(sre[i], sim[i]);
    }
    __syncthreads();

    // ---- phase 2: threads 0..99 build the folded G table (verified) ----
    if (threadIdx.x < 100) {
        const int ac = threadIdx.x / 10, bd = threadIdx.x % 10;
        const int a = PA[ac], c = PC[ac], b = PA[bd], d = PC[bd];

        auto evalS = [&](int j, int k, float* sv) {
            float ar[4] = {0,0,0,0}, ai[4] = {0,0,0,0};
#pragma unroll
            for (int i = 0; i < DIM; ++i) {
                const float2 wj = WT[j][i], wk = WT[k][i];
                const float pr = wj.x * wk.x + wj.y * wk.y;
                const float pi = wj.x * wk.y - wj.y * wk.x;
#pragma unroll
                for (int q = 0; q < 4; ++q) {
                    const float s = ((i >> (3 - q)) & 1) ? -1.f : 1.f;
                    ar[q] += s * pr; ai[q] += s * pi;
                }
            }
            const int m = (__builtin_popcount(j) - __builtin_popcount(k)) & 3;
#pragma unroll
            for (int q = 0; q < 4; ++q)
                sv[q] = (m == 0) ? ar[q] : (m == 1) ? -ai[q] : (m == 2) ? -ar[q] : ai[q];
        };

        float s1[4], s2[4];
        evalS(4 * a + b, 4 * c + d, s1);
        evalS(4 * a + d, 4 * c + b, s2);
        const float u = ((a < c) ? 2.f : 1.f) * ((b < d) ? 1.f : 0.5f);
        G4[ac * 10 + bd] = make_float4(u * (s1[0] + s2[0]), u * (s1[1] + s2[1]),
                                       u * (s1[2] + s2[2]), u * (s1[3] + s2[3]));
    }
    __syncthreads();

    // ---- phase 3: E batch elements per thread ----
    const int tid  = threadIdx.x;
    const int base = blockIdx.x * (256 * E) + tid;

    float hh[E][4], llp[E][10];
    float o0[E], o1[E], o2[E], o3[E];

#pragma unroll
    for (int e = 0; e < E; ++e) {
        const int gi = base + e * 256;
        const float4 xv = (gi < B) ? x[gi] : make_float4(0.f, 0.f, 0.f, 0.f);
        const float s0 = __sinf(0.5f * xv.x), c0 = __cosf(0.5f * xv.x);
        const float s1 = __sinf(0.5f * xv.y), c1 = __cosf(0.5f * xv.y);
        const float s2 = __sinf(0.5f * xv.z), c2 = __cosf(0.5f * xv.z);
        const float s3 = __sinf(0.5f * xv.w), c3 = __cosf(0.5f * xv.w);
        hh[e][0] = c0 * c1; hh[e][1] = c0 * s1; hh[e][2] = s0 * c1; hh[e][3] = s0 * s1;
        const float ll[4] = {c2 * c3, c2 * s3, s2 * c3, s2 * s3};
#pragma unroll
        for (int p = 0; p < 10; ++p) llp[e][p] = ll[PA[p]] * ll[PC[p]];
        o0[e] = o1[e] = o2[e] = o3[e] = 0.f;
    }

#pragma unroll
    for (int ac = 0; ac < 10; ++ac) {
        float hp[E];
#pragma unroll
        for (int e = 0; e < E; ++e) hp[e] = hh[e][PA[ac]] * hh[e][PC[ac]];
#pragma unroll
        for (int bd = 0; bd < 10; ++bd) {
            const float4 g = G4[ac * 10 + bd];          // broadcast ds_read_b128
#pragma unroll
            for (int e = 0; e < E; ++e) {
                const float coef = hp[e] * llp[e][bd];
                o0[e] += g.x * coef; o1[e] += g.y * coef;
                o2[e] += g.z * coef; o3[e] += g.w * coef;
            }
        }
        // cap G4-load hoisting across iterations (round-3 spill cause)
        __builtin_amdgcn_sched_barrier(0);
    }

#pragma unroll
    for (int e = 0; e < E; ++e) {
        const int gi = base + e * 256;
        if (gi < B) out[gi] = make_float4(o0[e], o1[e], o2[e], o3[e]);
    }
}

extern "C" void kernel_launch(void* const* d_in, const int* in_sizes, int n_in,
                              void* d_out, int out_size, void* d_ws, size_t ws_size,
                              hipStream_t stream)
{
    const float4* x = (const float4*)d_in[0];
    const float* w  = (const float*)d_in[1];
    float4* out     = (float4*)d_out;
    const int B = in_sizes[0] / NQ;
    const int block = 256;
    const int perBlock = block * E;
    const int grid = (B + perBlock - 1) / perBlock;
    qlayer_kernel<<<grid, block, 0, stream>>>(x, w, out, B);
}

// Round 7
// 103.523 us; speedup vs baseline: 4.6527x; 4.6527x over previous
//
#include <hip/hip_runtime.h>

#define NQ 4
#define DIM 16
#define E 4   // batch elements per thread

// o_q(b) = sum_{a<=c} hh_a hh_c * sum_{b<=d} ll_b ll_d * G_q[(a,c)][(b,d)]
// G: 10x10 float4 (1.6 KB LDS), built per-block from the weight unitary.
// Round-7: R4 structure + native __sinf/__cosf (ocml __sincosf was the
// VGPR/VALU hog) + PLAIN __launch_bounds__(256) (the ",4" in R6 made the
// allocator target 64 VGPRs -> total scratch spill, 450 us).

__global__ void __launch_bounds__(256)
qlayer_kernel(const float4* __restrict__ x,
              const float* __restrict__ weights,
              float4* __restrict__ out, int B)
{
    __shared__ __align__(16) float2 WT[DIM][DIM];       // WT[j][i] = W[i][j]
    __shared__ __align__(16) float4 G4[100];            // G[(ac)*10+(bd)]

    constexpr int PA[10] = {0,0,0,0,1,1,1,2,2,3};
    constexpr int PC[10] = {0,1,2,3,1,2,3,2,3,3};

    // ---- phase 1: threads 0..15 build W columns (verified) ----
    if (threadIdx.x < DIM) {
        const int k = threadIdx.x;
        float sre[DIM], sim[DIM];
#pragma unroll
        for (int i = 0; i < DIM; ++i) { sre[i] = (i == k) ? 1.f : 0.f; sim[i] = 0.f; }
#pragma unroll
        for (int l = 0; l < 3; ++l) {
#pragma unroll
            for (int p = 0; p < NQ; ++p) {
                const float h = 0.5f * weights[l * NQ + p];
                const float s = __sinf(h), c = __cosf(h);
                const int mask = 1 << (NQ - 1 - p);
#pragma unroll
                for (int i = 0; i < DIM; ++i) {
                    if (i & mask) continue;
                    const int jj = i | mask;
                    const float ar = sre[i], ai = sim[i];
                    const float br = sre[jj], bi = sim[jj];
                    sre[i]  = c * ar + s * bi;
                    sim[i]  = c * ai - s * br;
                    sre[jj] = c * br + s * ai;
                    sim[jj] = c * bi - s * ar;
                }
            }
#pragma unroll
            for (int p = 0; p < NQ; ++p) {
                const int t = (p + 1) % NQ;
                float tr[DIM], ti[DIM];
#pragma unroll
                for (int i = 0; i < DIM; ++i) {
                    const int src = i ^ ((((i >> (NQ - 1 - p)) & 1)) << (NQ - 1 - t));
                    tr[i] = sre[src]; ti[i] = sim[src];
                }
#pragma unroll
                for (int i = 0; i < DIM; ++i) { sre[i] = tr[i]; sim[i] = ti[i]; }
            }
        }
#pragma unroll
        for (int i = 0; i < DIM; ++i) WT[k][i] = make_float2(sre[i], sim[i]);
    }
    __syncthreads();

    // ---- phase 2: threads 0..99 build the folded G table (verified) ----
    if (threadIdx.x < 100) {
        const int ac = threadIdx.x / 10, bd = threadIdx.x % 10;
        const int a = PA[ac], c = PC[ac], b = PA[bd], d = PC[bd];

        auto evalS = [&](int j, int k, float* sv) {
            float ar[4] = {0,0,0,0}, ai[4] = {0,0,0,0};
#pragma unroll
            for (int i = 0; i < DIM; ++i) {
                const float2 wj = WT[j][i], wk = WT[k][i];
                const float pr = wj.x * wk.x + wj.y * wk.y;
                const float pi = wj.x * wk.y - wj.y * wk.x;
#pragma unroll
                for (int q = 0; q < 4; ++q) {
                    const float s = ((i >> (3 - q)) & 1) ? -1.f : 1.f;
                    ar[q] += s * pr; ai[q] += s * pi;
                }
            }
            const int m = (__builtin_popcount(j) - __builtin_popcount(k)) & 3;
#pragma unroll
            for (int q = 0; q < 4; ++q)
                sv[q] = (m == 0) ? ar[q] : (m == 1) ? -ai[q] : (m == 2) ? -ar[q] : ai[q];
        };

        float s1[4], s2[4];
        evalS(4 * a + b, 4 * c + d, s1);
        evalS(4 * a + d, 4 * c + b, s2);
        const float u = ((a < c) ? 2.f : 1.f) * ((b < d) ? 1.f : 0.5f);
        G4[ac * 10 + bd] = make_float4(u * (s1[0] + s2[0]), u * (s1[1] + s2[1]),
                                       u * (s1[2] + s2[2]), u * (s1[3] + s2[3]));
    }
    __syncthreads();

    // ---- phase 3: E batch elements per thread ----
    const int tid  = threadIdx.x;
    const int base = blockIdx.x * (256 * E) + tid;

    float hh[E][4], llp[E][10];
    float o0[E], o1[E], o2[E], o3[E];

#pragma unroll
    for (int e = 0; e < E; ++e) {
        const int gi = base + e * 256;
        const float4 xv = (gi < B) ? x[gi] : make_float4(0.f, 0.f, 0.f, 0.f);
        const float s0 = __sinf(0.5f * xv.x), c0 = __cosf(0.5f * xv.x);
        const float s1 = __sinf(0.5f * xv.y), c1 = __cosf(0.5f * xv.y);
        const float s2 = __sinf(0.5f * xv.z), c2 = __cosf(0.5f * xv.z);
        const float s3 = __sinf(0.5f * xv.w), c3 = __cosf(0.5f * xv.w);
        hh[e][0] = c0 * c1; hh[e][1] = c0 * s1; hh[e][2] = s0 * c1; hh[e][3] = s0 * s1;
        const float ll[4] = {c2 * c3, c2 * s3, s2 * c3, s2 * s3};
#pragma unroll
        for (int p = 0; p < 10; ++p) llp[e][p] = ll[PA[p]] * ll[PC[p]];
        o0[e] = o1[e] = o2[e] = o3[e] = 0.f;
    }

#pragma unroll
    for (int ac = 0; ac < 10; ++ac) {
        float hp[E];
#pragma unroll
        for (int e = 0; e < E; ++e) hp[e] = hh[e][PA[ac]] * hh[e][PC[ac]];
#pragma unroll
        for (int bd = 0; bd < 10; ++bd) {
            const float4 g = G4[ac * 10 + bd];          // broadcast ds_read_b128
#pragma unroll
            for (int e = 0; e < E; ++e) {
                const float coef = hp[e] * llp[e][bd];
                o0[e] += g.x * coef; o1[e] += g.y * coef;
                o2[e] += g.z * coef; o3[e] += g.w * coef;
            }
        }
        // cap G4-load hoisting across iterations (round-3 spill cause)
        __builtin_amdgcn_sched_barrier(0);
    }

#pragma unroll
    for (int e = 0; e < E; ++e) {
        const int gi = base + e * 256;
        if (gi < B) out[gi] = make_float4(o0[e], o1[e], o2[e], o3[e]);
    }
}

extern "C" void kernel_launch(void* const* d_in, const int* in_sizes, int n_in,
                              void* d_out, int out_size, void* d_ws, size_t ws_size,
                              hipStream_t stream)
{
    const float4* x = (const float4*)d_in[0];
    const float* w  = (const float*)d_in[1];
    float4* out     = (float4*)d_out;
    const int B = in_sizes[0] / NQ;
    const int block = 256;
    const int perBlock = block * E;
    const int grid = (B + perBlock - 1) / perBlock;
    qlayer_kernel<<<grid, block, 0, stream>>>(x, w, out, B);
}

// Round 8
// 94.427 us; speedup vs baseline: 5.1009x; 1.0963x over previous
//
#include <hip/hip_runtime.h>

#define NQ 4
#define DIM 16
#define E 4   // batch elements per thread

// Split design (round 8):
//  qlayer_prep (1 block): build weight unitary W, fold into real symmetric
//    product-form table G (10x10 float4), write to d_ws. This code is the
//    VGPR hog (evalS high-watermark = 228 VGPR) -- keep it OUT of the hot
//    kernel's compilation.
//  qlayer_main: stage G (1.6 KB) global->LDS (one load/thread), then
//    o_q = sum_{a<=c} hh_a hh_c sum_{b<=d} ll_b ll_d G_q[(ac)][(bd)].
//    No llp array (ll products inline) -> ~110 VGPR target.

constexpr int PA[10] = {0,0,0,0,1,1,1,2,2,3};
constexpr int PC[10] = {0,1,2,3,1,2,3,2,3,3};

__global__ void __launch_bounds__(128)
qlayer_prep(const float* __restrict__ weights, float4* __restrict__ gw)
{
    __shared__ __align__(16) float2 WT[DIM][DIM];   // WT[j][i] = W[i][j]

    // ---- threads 0..15: build W columns (verified R1-R7) ----
    if (threadIdx.x < DIM) {
        const int k = threadIdx.x;
        float sre[DIM], sim[DIM];
#pragma unroll
        for (int i = 0; i < DIM; ++i) { sre[i] = (i == k) ? 1.f : 0.f; sim[i] = 0.f; }
#pragma unroll
        for (int l = 0; l < 3; ++l) {
#pragma unroll
            for (int p = 0; p < NQ; ++p) {
                const float h = 0.5f * weights[l * NQ + p];
                const float s = __sinf(h), c = __cosf(h);
                const int mask = 1 << (NQ - 1 - p);
#pragma unroll
                for (int i = 0; i < DIM; ++i) {
                    if (i & mask) continue;
                    const int jj = i | mask;
                    const float ar = sre[i], ai = sim[i];
                    const float br = sre[jj], bi = sim[jj];
                    sre[i]  = c * ar + s * bi;
                    sim[i]  = c * ai - s * br;
                    sre[jj] = c * br + s * ai;
                    sim[jj] = c * bi - s * ar;
                }
            }
#pragma unroll
            for (int p = 0; p < NQ; ++p) {
                const int t = (p + 1) % NQ;
                float tr[DIM], ti[DIM];
#pragma unroll
                for (int i = 0; i < DIM; ++i) {
                    const int src = i ^ ((((i >> (NQ - 1 - p)) & 1)) << (NQ - 1 - t));
                    tr[i] = sre[src]; ti[i] = sim[src];
                }
#pragma unroll
                for (int i = 0; i < DIM; ++i) { sre[i] = tr[i]; sim[i] = ti[i]; }
            }
        }
#pragma unroll
        for (int i = 0; i < DIM; ++i) WT[k][i] = make_float2(sre[i], sim[i]);
    }
    __syncthreads();

    // ---- threads 0..99: fold into G, write to global (verified R2-R7) ----
    if (threadIdx.x < 100) {
        const int ac = threadIdx.x / 10, bd = threadIdx.x % 10;
        const int a = PA[ac], c = PC[ac], b = PA[bd], d = PC[bd];

        auto evalS = [&](int j, int k, float* sv) {
            float ar[4] = {0,0,0,0}, ai[4] = {0,0,0,0};
#pragma unroll
            for (int i = 0; i < DIM; ++i) {
                const float2 wj = WT[j][i], wk = WT[k][i];
                const float pr = wj.x * wk.x + wj.y * wk.y;
                const float pi = wj.x * wk.y - wj.y * wk.x;
#pragma unroll
                for (int q = 0; q < 4; ++q) {
                    const float s = ((i >> (3 - q)) & 1) ? -1.f : 1.f;
                    ar[q] += s * pr; ai[q] += s * pi;
                }
            }
            const int m = (__builtin_popcount(j) - __builtin_popcount(k)) & 3;
#pragma unroll
            for (int q = 0; q < 4; ++q)
                sv[q] = (m == 0) ? ar[q] : (m == 1) ? -ai[q] : (m == 2) ? -ar[q] : ai[q];
        };

        float s1[4], s2[4];
        evalS(4 * a + b, 4 * c + d, s1);
        evalS(4 * a + d, 4 * c + b, s2);
        const float u = ((a < c) ? 2.f : 1.f) * ((b < d) ? 1.f : 0.5f);
        gw[ac * 10 + bd] = make_float4(u * (s1[0] + s2[0]), u * (s1[1] + s2[1]),
                                       u * (s1[2] + s2[2]), u * (s1[3] + s2[3]));
    }
}

__global__ void __launch_bounds__(256)
qlayer_main(const float4* __restrict__ x,
            const float4* __restrict__ gw,
            float4* __restrict__ out, int B)
{
    __shared__ __align__(16) float4 G4[100];
    if (threadIdx.x < 100) G4[threadIdx.x] = gw[threadIdx.x];
    __syncthreads();

    const int tid  = threadIdx.x;
    const int base = blockIdx.x * (256 * E) + tid;

    float hh[E][4], ll[E][4];
    float o0[E], o1[E], o2[E], o3[E];

#pragma unroll
    for (int e = 0; e < E; ++e) {
        const int gi = base + e * 256;
        const float4 xv = (gi < B) ? x[gi] : make_float4(0.f, 0.f, 0.f, 0.f);
        const float s0 = __sinf(0.5f * xv.x), c0 = __cosf(0.5f * xv.x);
        const float s1 = __sinf(0.5f * xv.y), c1 = __cosf(0.5f * xv.y);
        const float s2 = __sinf(0.5f * xv.z), c2 = __cosf(0.5f * xv.z);
        const float s3 = __sinf(0.5f * xv.w), c3 = __cosf(0.5f * xv.w);
        hh[e][0] = c0 * c1; hh[e][1] = c0 * s1; hh[e][2] = s0 * c1; hh[e][3] = s0 * s1;
        ll[e][0] = c2 * c3; ll[e][1] = c2 * s3; ll[e][2] = s2 * c3; ll[e][3] = s2 * s3;
        o0[e] = o1[e] = o2[e] = o3[e] = 0.f;
    }

#pragma unroll
    for (int ac = 0; ac < 10; ++ac) {
        float hp[E];
#pragma unroll
        for (int e = 0; e < E; ++e) hp[e] = hh[e][PA[ac]] * hh[e][PC[ac]];
#pragma unroll
        for (int bd = 0; bd < 10; ++bd) {
            const float4 g = G4[ac * 10 + bd];          // broadcast ds_read_b128
#pragma unroll
            for (int e = 0; e < E; ++e) {
                const float coef = hp[e] * (ll[e][PA[bd]] * ll[e][PC[bd]]);
                o0[e] += g.x * coef; o1[e] += g.y * coef;
                o2[e] += g.z * coef; o3[e] += g.w * coef;
            }
        }
        // cap G4-load hoisting across ac-iterations (round-3 spill cause)
        __builtin_amdgcn_sched_barrier(0);
    }

#pragma unroll
    for (int e = 0; e < E; ++e) {
        const int gi = base + e * 256;
        if (gi < B) out[gi] = make_float4(o0[e], o1[e], o2[e], o3[e]);
    }
}

extern "C" void kernel_launch(void* const* d_in, const int* in_sizes, int n_in,
                              void* d_out, int out_size, void* d_ws, size_t ws_size,
                              hipStream_t stream)
{
    const float4* x = (const float4*)d_in[0];
    const float* w  = (const float*)d_in[1];
    float4* out     = (float4*)d_out;
    float4* gw      = (float4*)d_ws;     // 100 * 16 B = 1.6 KB
    const int B = in_sizes[0] / NQ;

    qlayer_prep<<<1, 128, 0, stream>>>(w, gw);

    const int block = 256;
    const int perBlock = block * E;
    const int grid = (B + perBlock - 1) / perBlock;
    qlayer_main<<<grid, block, 0, stream>>>(x, gw, out, B);
}